// Round 7
// baseline (28.791 us; speedup 1.0000x reference)
//
#include <hip/hip_runtime.h>
#include <cstdint>
#include <cstddef>

#define MAXG 128

// ---------------- compile-time: reproduce numpy legacy RandomState(42) ----------------
namespace ct {

struct MT19937 {
  uint32_t mt[624] = {};
  int mti = 0;
  constexpr void seed(uint32_t s) {
    mt[0] = s;
    for (int i = 1; i < 624; i++)
      mt[i] = 1812433253u * (mt[i-1] ^ (mt[i-1] >> 30)) + (uint32_t)i;
    mti = 624;
  }
  constexpr uint32_t next() {
    if (mti >= 624) {
      for (int i = 0; i < 624; i++) {
        uint32_t y = (mt[i] & 0x80000000u) | (mt[(i+1) % 624] & 0x7fffffffu);
        mt[i] = mt[(i+397) % 624] ^ (y >> 1) ^ ((y & 1u) ? 2567483615u : 0u);
      }
      mti = 0;
    }
    uint32_t y = mt[mti++];
    y ^= y >> 11; y ^= (y << 7) & 2636928640u; y ^= (y << 15) & 4022730752u; y ^= y >> 18;
    return y;
  }
  constexpr double rdouble() {               // legacy rk_double: two 32-bit draws
    uint32_t a = next() >> 5, b = next() >> 6;
    return ((double)a * 67108864.0 + (double)b) / 9007199254740992.0;
  }
  constexpr uint32_t masked32(uint32_t rng, uint32_t mask) {  // legacy randint
    uint32_t v = next() & mask;
    while (v > rng) v = next() & mask;
    return v;
  }
  constexpr uint32_t interval(uint32_t mx) {  // random_interval (shuffle)
    if (!mx) return 0;
    uint32_t mask = mx;
    mask |= mask >> 1; mask |= mask >> 2; mask |= mask >> 4; mask |= mask >> 8; mask |= mask >> 16;
    uint32_t v = next() & mask;
    while (v > mx) v = next() & mask;
    return v;
  }
};

// gate code: bits[1:0] = kind (0=RX,1=RY,2=RZ,3=CNOT)
//   R:    bits[5:2] = wire bit mask (8>>wire), bits[10:6] = weight index l*8+i
//   CNOT: bits[5:2] = control bit mask,        bits[9:6]  = target bit mask
struct CG { int n = 0; int code[MAXG] = {}; };

constexpr CG build_gates_ct() {
  CG gl{};
  MT19937 rng{};
  rng.seed(42);
  for (int l = 0; l < 4; l++) {
    int i = 0;
    while (i < 8) {
      if (rng.rdouble() > 0.3) {
        int g = (int)rng.masked32(2, 3);   // randint(3)
        int w = (int)rng.masked32(3, 3);   // randint(4)
        int widx = l * 8 + i;
        if (gl.n < MAXG) gl.code[gl.n++] = g | ((8 >> w) << 2) | (widx << 6);
        i++;
      } else {
        int perm[4] = {0, 1, 2, 3};
        for (int ii = 3; ii >= 1; ii--) {
          int j = (int)rng.interval((uint32_t)ii);
          int tmp = perm[ii]; perm[ii] = perm[j]; perm[j] = tmp;
        }
        int cw = perm[0], tw = perm[1];
        if (gl.n < MAXG) gl.code[gl.n++] = 3 | ((8 >> cw) << 2) | ((8 >> tw) << 6);
      }
    }
  }
  return gl;
}

constexpr CG GL = build_gates_ct();

} // namespace ct

// Native trig: v_sin_f32 / v_cos_f32 take REVOLUTIONS. All our half-angles are in
// [0, pi) (weights in [0,2pi)) or [0, 0.5] (pixel means in [0,1)) -> |rev| < 0.5,
// no range reduction needed, ~1ulp in this range. Computes sin(a/2), cos(a/2).
__device__ __forceinline__ void half_sincos(float a, float& s, float& c) {
  const float r = a * 0.07957747154594767f;   // a * 0.5 / (2*pi)
  s = __builtin_amdgcn_sinf(r);
  c = __builtin_amdgcn_cosf(r);
}

// ---------------- gate chain: template recursion => static indexing GUARANTEED ------
template <int G>
__device__ __forceinline__ void apply_gates(float (&sr)[16], float (&si)[16],
                                            const float* __restrict__ w) {
  if constexpr (G < ct::GL.n) {
    constexpr int code = ct::GL.code[G];
    constexpr int kind = code & 3;
    if constexpr (kind == 3) {              // CNOT: pure register permutation
      constexpr int cbit = (code >> 2) & 15, tbit = (code >> 6) & 15;
      float tr[16], ti[16];
      #pragma unroll
      for (int k = 0; k < 16; k++) {
        const int src = (k & cbit) ? (k ^ tbit) : k;   // all ct-const
        tr[k] = sr[src]; ti[k] = si[src];
      }
      #pragma unroll
      for (int k = 0; k < 16; k++) { sr[k] = tr[k]; si[k] = ti[k]; }
    } else {
      constexpr int bit  = (code >> 2) & 15;
      constexpr int widx = (code >> 6) & 31;
      float sh, ch;
      half_sincos(w[widx], sh, ch);         // native: 1 mul + v_sin + v_cos
      float tr[16], ti[16];
      #pragma unroll
      for (int k = 0; k < 16; k++) {
        const int p = k ^ bit;
        if constexpr (kind == 0) {          // RX
          tr[k] = ch * sr[k] + sh * si[p];
          ti[k] = ch * si[k] - sh * sr[p];
        } else if constexpr (kind == 1) {   // RY
          if (k & bit) { tr[k] = ch * sr[k] + sh * sr[p]; ti[k] = ch * si[k] + sh * si[p]; }
          else         { tr[k] = ch * sr[k] - sh * sr[p]; ti[k] = ch * si[k] - sh * si[p]; }
        } else {                            // RZ
          if (k & bit) { tr[k] = ch * sr[k] - sh * si[k]; ti[k] = ch * si[k] + sh * sr[k]; }
          else         { tr[k] = ch * sr[k] + sh * si[k]; ti[k] = ch * si[k] - sh * sr[k]; }
        }
      }
      #pragma unroll
      for (int k = 0; k < 16; k++) { sr[k] = tr[k]; si[k] = ti[k]; }
    }
    apply_gates<G + 1>(sr, si, w);
  }
}

// ---------------- kernel 1: build U, one wave, all-register ----------------
__global__ __launch_bounds__(64) void build_u(const float* __restrict__ w,
                                              float* __restrict__ ws) {
  const int c = threadIdx.x & 15;
  float sr[16], si[16];
  #pragma unroll
  for (int k = 0; k < 16; k++) { sr[k] = (k == c) ? 1.0f : 0.0f; si[k] = 0.0f; }

  apply_gates<0>(sr, si, w);

  if (threadIdx.x < 16) {
    float2* o = (float2*)ws;               // interleaved (re,im), float2 idx = k*16 + col
    #pragma unroll
    for (int k = 0; k < 16; k++) o[k * 16 + c] = make_float2(sr[k], si[k]);
  }
}

// ---------------- kernel 2: 4 patches/thread + zero-fill, U broadcast from LDS ------
// 512 blocks x 256 thr; thread = (b, jj, q) computes out (rows {jj,64+jj} x cols
// {q,64+q}) and 12 grid-strided zero float4s. P=4 amortizes the 128 ds_read_b128 of
// U over 4 patches (LDS pipe was ~8.5us/CU at P=2 -> ~4.3). Zero-writes stay here
// (qonv is not store-BW-bound, so they ride along nearly free; R6's separate fill
// kernel serialized them: +3.6us).
__global__ __launch_bounds__(256) void qonv_main(const float* __restrict__ img,
                                                 const float* __restrict__ uws,
                                                 float* __restrict__ out) {
  __shared__ float4 U4[128];               // U4[k*8+i2] = (re_{2i2}, im_{2i2}, re_{2i2+1}, im_{2i2+1})
  int t = threadIdx.x;
  if (t < 128) U4[t] = ((const float4*)uws)[t];

  unsigned tid = blockIdx.x * 256u + (unsigned)t;
  float4* o = (float4*)out;                // one float4 = 4 channels of one (b,r,c)

  // ---- zero region: rows 0..127 x cols 128..255 (16384 f4/b) + rows 128..255 (32768 f4/b)
  {
    const unsigned PERB = 49152u;
    const float4 z = make_float4(0.f, 0.f, 0.f, 0.f);
    unsigned zi = tid;
    #pragma unroll
    for (int it = 0; it < 12; it++) {      // 131072 thr x 12 = 1572864 = 32*PERB
      unsigned b = zi / PERB;              // magic-mul
      unsigned r = zi - b * PERB;
      unsigned row, col;
      if (r < 16384u) { row = r >> 7;              col = 128u + (r & 127u); }
      else            { unsigned r2 = r - 16384u;  row = 128u + (r2 >> 8); col = r2 & 255u; }
      o[((size_t)b * 256u + row) * 256u + col] = z;
      zi += 131072u;
    }
  }

  int q  = tid & 63;                       // col group 0..63
  int jj = (tid >> 6) & 63;                // row group 0..63
  int b  = tid >> 12;                      // batch 0..31

  const float inv3 = 1.0f / 3.0f;
  float s16[4][16];
  #pragma unroll
  for (int pr = 0; pr < 2; pr++) {
    const float* row0 = img + (size_t)(b * 512 + 2 * jj + 128 * pr) * 1536;
    const float* row1 = row0 + 1536;
    #pragma unroll
    for (int pc = 0; pc < 2; pc++) {
      const int p = pr * 2 + pc;
      int off = 384 * pc + 6 * q;          // floats; 8B-aligned
      float2 x0 = *(const float2*)(row0 + off);
      float2 x1 = *(const float2*)(row0 + off + 2);
      float2 x2 = *(const float2*)(row0 + off + 4);
      float2 y0 = *(const float2*)(row1 + off);
      float2 y1 = *(const float2*)(row1 + off + 2);
      float2 y2 = *(const float2*)(row1 + off + 4);
      float a0 = (x0.x + x0.y + x1.x) * inv3;   // (r0,c0)
      float a1 = (x1.y + x2.x + x2.y) * inv3;   // (r0,c1)
      float a2 = (y0.x + y0.y + y1.x) * inv3;   // (r1,c0)
      float a3 = (y1.y + y2.x + y2.y) * inv3;   // (r1,c1)
      float c0, s0, c1, s1, c2, s2, c3, s3;
      half_sincos(a0, s0, c0);
      half_sincos(a1, s1, c1);
      half_sincos(a2, s2, c2);
      half_sincos(a3, s3, c3);
      float A[4] = {c0*c1, c0*s1, s0*c1, s0*s1};
      float B[4] = {c2*c3, c2*s3, s2*c3, s2*s3};
      #pragma unroll
      for (int hi = 0; hi < 4; hi++)
        #pragma unroll
        for (int lo = 0; lo < 4; lo++)
          s16[p][hi * 4 + lo] = A[hi] * B[lo];
    }
  }

  float acc[4][4];
  #pragma unroll
  for (int p = 0; p < 4; p++)
    #pragma unroll
    for (int c = 0; c < 4; c++) acc[p][c] = 0.0f;

  __syncthreads();                         // U4 ready (staged before zero-fill)

  #pragma unroll
  for (int k = 0; k < 16; k++) {
    float2 amp[4];                         // (.x = re, .y = im) adjacent -> pk_fma bait
    #pragma unroll
    for (int p = 0; p < 4; p++) amp[p] = make_float2(0.f, 0.f);
    #pragma unroll
    for (int i2 = 0; i2 < 8; i2++) {
      float4 u = U4[k * 8 + i2];
      #pragma unroll
      for (int p = 0; p < 4; p++) {
        const float se = s16[p][2*i2], so = s16[p][2*i2+1];
        amp[p].x += u.x * se + u.z * so;
        amp[p].y += u.y * se + u.w * so;
      }
    }
    #pragma unroll
    for (int p = 0; p < 4; p++) {
      float pk = amp[p].x*amp[p].x + amp[p].y*amp[p].y;
      #pragma unroll
      for (int ch = 0; ch < 4; ch++) {
        if (k & (8 >> ch)) acc[p][ch] -= pk; else acc[p][ch] += pk;
      }
    }
  }

  size_t rowA = ((size_t)b * 256 + jj) * 256;          // out-row jj
  size_t rowB = ((size_t)b * 256 + 64 + jj) * 256;     // out-row 64+jj
  o[rowA + q]      = make_float4(acc[0][0], acc[0][1], acc[0][2], acc[0][3]);
  o[rowA + 64 + q] = make_float4(acc[1][0], acc[1][1], acc[1][2], acc[1][3]);
  o[rowB + q]      = make_float4(acc[2][0], acc[2][1], acc[2][2], acc[2][3]);
  o[rowB + 64 + q] = make_float4(acc[3][0], acc[3][1], acc[3][2], acc[3][3]);
}

extern "C" void kernel_launch(void* const* d_in, const int* in_sizes, int n_in,
                              void* d_out, int out_size, void* d_ws, size_t ws_size,
                              hipStream_t stream) {
  const float* img = (const float*)d_in[0];
  const float* wts = (const float*)d_in[1];
  float* out = (float*)d_out;

  build_u<<<1, 64, 0, stream>>>(wts, (float*)d_ws);
  qonv_main<<<512, 256, 0, stream>>>(img, (const float*)d_ws, out);
}